// Round 4
// baseline (450.504 us; speedup 1.0000x reference)
//
#include <hip/hip_runtime.h>
#include <hip/hip_bf16.h>
#include <math.h>

typedef __hip_bfloat16 hbf16;
typedef __attribute__((ext_vector_type(8))) short short8;   // 8 bf16 (4 VGPRs)
typedef __attribute__((ext_vector_type(4))) float f32x4;

static const long QS = 2097152;  // 512*4096 per-batch q/k/v/out elems

__device__ __forceinline__ unsigned short f2bf(float f) {
    hbf16 h = __float2bfloat16(f);
    return *reinterpret_cast<unsigned short*>(&h);
}
__device__ __forceinline__ float bf2f(unsigned short u) {
    unsigned x = ((unsigned)u) << 16;
    return __uint_as_float(x);
}
__device__ __forceinline__ unsigned pk2(float a, float b) {
    return (unsigned)f2bf(a) | ((unsigned)f2bf(b) << 16);
}

// async 16-B global->LDS (wave-uniform LDS base; HW adds lane*16)
__device__ __forceinline__ void gload16(const void* g, void* l) {
    __builtin_amdgcn_global_load_lds(
        (const __attribute__((address_space(1))) void*)g,
        (__attribute__((address_space(3))) void*)l, 16, 0, 0);
}

// ---------------------------------------------------------------------------
// convmm: 1x1-conv GEMM with fp32 transposed operand, K=512, BK=32.
// Trans-side tile = 256 rows (p), direct-side (weights) = 64 rows.
// PTM=true  (conv-T): C[m=p 256][n=o 64]   A=trans(q/k), B=W direct
// PTM=false (conv-N): C[m=o 64][n=p 256]   A=W direct,  B=trans(v)
// Key point: fp32 reads are 1-KB contiguous rows (256 floats) -> DRAM
// row-buffer friendly, unlike the old 256-B x 16-KB-stride pattern.
// Padded LDS pitch (40 shorts) makes all ds accesses ~2-way = free.
// ---------------------------------------------------------------------------
template <bool PTM, bool DUAL>
__global__ __launch_bounds__(256) void convmm(
    const float* __restrict__ X0, const float* __restrict__ X1,
    const short* __restrict__ W, long selW,
    short* __restrict__ C, long selC,
    int ldc, long bsX, long bsC)
{
    __shared__ __align__(16) float Lf[32 * 256];   // 32 KB fp32 [kc 32][p 256]
    __shared__ __align__(16) short Ps[256 * 40];   // 20 KB padded bf16 [p][k 32 + pad]
    __shared__ __align__(16) short Ws[64 * 40];    //  5 KB padded bf16 [o][k 32 + pad]

    const int tid = threadIdx.x;
    const int w = tid >> 6, lane = tid & 63;
    const int quad = lane >> 4, l16 = lane & 15;

    int bz = blockIdx.z, sel = 0;
    if constexpr (DUAL) { sel = bz & 1; bz >>= 1; }

    const int p0 = (PTM ? blockIdx.y : blockIdx.x) * 256;  // trans-tile base
    const int w0 = (PTM ? blockIdx.x : blockIdx.y) * 64;   // weight-tile base

    const float* X = ((DUAL && sel) ? X1 : X0) + (long)bz * bsX;
    const short* Wp = W + (long)sel * selW;
    short* Cp = C + (long)bz * bsC + (long)sel * selC;

    // W reg-staging assignment: thread -> (row, k-chunk)
    const int wr = tid >> 2, wc = tid & 3;
    short8 wreg;

    f32x4 acc[4][4];
#pragma unroll
    for (int i = 0; i < 4; ++i)
#pragma unroll
        for (int j = 0; j < 4; ++j) acc[i][j] = (f32x4){0.f, 0.f, 0.f, 0.f};

    // issue the 32x256 fp32 tile (8 rounds x 4 KB); 1-KB contiguous per row
    auto issueX = [&](int k0) {
#pragma unroll
        for (int i = 0; i < 8; ++i) {
            int e = i * 1024 + tid * 4;          // per-lane elem for global addr
            int kc = e >> 8, p = e & 255;
            gload16(X + (long)(k0 + kc) * 4096 + p0 + p,
                    Lf + i * 1024 + w * 256);    // wave-uniform LDS base
        }
    };
    auto loadW = [&](int k0) {
        wreg = *reinterpret_cast<const short8*>(
            &Wp[(long)(w0 + wr) * 512 + k0 + wc * 8]);
    };

    issueX(0);
    loadW(0);

    for (int k0 = 0; k0 < 512; k0 += 32) {
        __syncthreads();   // drains vm: Lf ready; prev frag reads done

        // transpose + cast: Lf[kc][p] -> Ps[p][kc] (padded)
#pragma unroll
        for (int u = 0; u < 4; ++u) {
            float f[8];
#pragma unroll
            for (int j = 0; j < 8; ++j) f[j] = Lf[(u * 8 + j) * 256 + tid];
            uint4 pk;
            pk.x = pk2(f[0], f[1]);
            pk.y = pk2(f[2], f[3]);
            pk.z = pk2(f[4], f[5]);
            pk.w = pk2(f[6], f[7]);
            *reinterpret_cast<uint4*>(&Ps[tid * 40 + u * 8]) = pk;
        }
        *reinterpret_cast<short8*>(&Ws[wr * 40 + wc * 8]) = wreg;

        __syncthreads();   // LDS visible; Lf free for prefetch

        if (k0 + 32 < 512) { issueX(k0 + 32); loadW(k0 + 32); }

        short8 af[4], bf[4];
#pragma unroll
        for (int mt = 0; mt < 4; ++mt) {
            int r = PTM ? (w * 64 + mt * 16 + l16) : (mt * 16 + l16);
            const short* base = PTM ? Ps : Ws;
            af[mt] = *reinterpret_cast<const short8*>(&base[r * 40 + quad * 8]);
        }
#pragma unroll
        for (int nt = 0; nt < 4; ++nt) {
            int r = PTM ? (nt * 16 + l16) : (w * 64 + nt * 16 + l16);
            const short* base = PTM ? Ws : Ps;
            bf[nt] = *reinterpret_cast<const short8*>(&base[r * 40 + quad * 8]);
        }
#pragma unroll
        for (int mt = 0; mt < 4; ++mt)
#pragma unroll
            for (int nt = 0; nt < 4; ++nt)
                acc[mt][nt] = __builtin_amdgcn_mfma_f32_16x16x32_bf16(
                    af[mt], bf[nt], acc[mt][nt], 0, 0, 0);
    }

    // Epilogue: C/D layout col = lane&15, row = quad*4 + reg.
#pragma unroll
    for (int mt = 0; mt < 4; ++mt)
#pragma unroll
        for (int nt = 0; nt < 4; ++nt)
#pragma unroll
            for (int reg = 0; reg < 4; ++reg) {
                int gr = (PTM ? (blockIdx.y * 256 + w * 64 + mt * 16)
                              : (blockIdx.y * 64 + mt * 16)) + quad * 4 + reg;
                int gc = (PTM ? (blockIdx.x * 64 + nt * 16)
                              : (blockIdx.x * 256 + w * 64 + nt * 16)) + l16;
                Cp[(long)gr * ldc + gc] = (short)f2bf(acc[mt][nt][reg]);
            }
}

// ---------------------------------------------------------------------------
// BK=64 direct staging for the bf16 GEMMs (proven R2 path).
// LDS row r = 64 shorts (128 B) = 8 chunk slots; slot s holds chunk s^(r&7).
// ---------------------------------------------------------------------------
template <int R>
__device__ __forceinline__ void stage_direct(const short* P, int ld, int row0,
                                             long koff, short* Ls) {
    const int tid = threadIdx.x;
    const int w = tid >> 6, lane = tid & 63;
    const int lrow = lane >> 3;
    const int s = lane & 7;
#pragma unroll
    for (int j = 0; j < R / 32; ++j) {
        int rowbase = w * (R / 4) + j * 8;
        int r = rowbase + lrow;
        int g = s ^ (r & 7);
        const short* ga = P + (long)(row0 + r) * ld + koff + g * 8;
        gload16(ga, Ls + rowbase * 64);
    }
}

#define EPI_BF 0   // bf16 C[row][col], ldc
#define EPI_YT 1   // AV: scatter to YtvT[4096][256]
#define EPI_OUT 2  // fp32 out + q + v residual, ldc=4096

// Generic NT MFMA GEMM (direct bf16 operands only): C[m][n] = sum_k A[m][k]B[n][k]
template <int TM, int TN, int EPI>
__global__ __launch_bounds__(256) void mm(
    const short* __restrict__ A, const short* __restrict__ B,
    void* __restrict__ C, const float* __restrict__ Rq, const float* __restrict__ Rv,
    int K, int lda, int ldb, int ldc, int kmask, int kshift, long kpanel,
    long bsA, long bsB, long bsC, long bsR)
{
    __shared__ __align__(16) short As[TM * 64];
    __shared__ __align__(16) short Bs[TN * 64];

    const int tid = threadIdx.x;
    const int w = tid >> 6, lane = tid & 63;
    const int quad = lane >> 4, l16 = lane & 15;
    const int m0 = blockIdx.y * TM;
    const int n0 = blockIdx.x * TN;
    const int bz = blockIdx.z;

    A += (long)bz * bsA;
    B += (long)bz * bsB;
    const long cb = (long)bz * bsC;
    if constexpr (EPI == EPI_OUT) { Rq += (long)bz * bsR; Rv += (long)bz * bsR; }

    constexpr int WM = TM / 2;
    constexpr int MT = WM / 16;
    const int wm = (w & 1) * WM;
    const int wn = (w >> 1) * 64;

    f32x4 acc[MT][4];
#pragma unroll
    for (int i = 0; i < MT; ++i)
#pragma unroll
        for (int j = 0; j < 4; ++j) acc[i][j] = (f32x4){0.f, 0.f, 0.f, 0.f};

    for (int k0 = 0; k0 < K; k0 += 64) {
        __syncthreads();
        long koff = (long)(k0 & kmask) + (long)(k0 >> kshift) * kpanel;
        stage_direct<TM>(A, lda, m0, koff, As);
        stage_direct<TN>(B, ldb, n0, koff, Bs);
        __syncthreads();

#pragma unroll
        for (int ks = 0; ks < 2; ++ks) {
            short8 af[MT], bfr[4];
#pragma unroll
            for (int mt = 0; mt < MT; ++mt) {
                int r = wm + mt * 16 + l16;
                int s = (ks * 4 + quad) ^ (r & 7);
                af[mt] = *reinterpret_cast<const short8*>(&As[r * 64 + s * 8]);
            }
#pragma unroll
            for (int nt = 0; nt < 4; ++nt) {
                int r = wn + nt * 16 + l16;
                int s = (ks * 4 + quad) ^ (r & 7);
                bfr[nt] = *reinterpret_cast<const short8*>(&Bs[r * 64 + s * 8]);
            }
#pragma unroll
            for (int mt = 0; mt < MT; ++mt)
#pragma unroll
                for (int nt = 0; nt < 4; ++nt)
                    acc[mt][nt] = __builtin_amdgcn_mfma_f32_16x16x32_bf16(
                        af[mt], bfr[nt], acc[mt][nt], 0, 0, 0);
        }
    }

#pragma unroll
    for (int mt = 0; mt < MT; ++mt)
#pragma unroll
        for (int nt = 0; nt < 4; ++nt)
#pragma unroll
            for (int reg = 0; reg < 4; ++reg) {
                int gr = m0 + wm + mt * 16 + quad * 4 + reg;
                int gc = n0 + wn + nt * 16 + l16;
                float vacc = acc[mt][nt][reg];
                if constexpr (EPI == EPI_BF) {
                    ((short*)C)[cb + (long)gr * ldc + gc] = (short)f2bf(vacc);
                } else if constexpr (EPI == EPI_YT) {
                    long a = (long)gc * 256 + (long)(gr & 1) * 524288 + (gr >> 1);
                    ((short*)C)[cb + a] = (short)f2bf(vacc);
                } else {
                    long a = (long)gr * 4096 + gc;
                    ((float*)C)[cb + a] = vacc + Rq[a] + Rv[a];
                }
            }
}

// Row softmax of T[nrows][2048] bf16 in place (one block per row).
__global__ __launch_bounds__(256) void softmax_row(short* __restrict__ T) {
    const int row = blockIdx.x;
    const int tid = threadIdx.x;
    const int w = tid >> 6, lane = tid & 63;
    __shared__ float red[8];

    uint4 u = *reinterpret_cast<const uint4*>(&T[(long)row * 2048 + tid * 8]);
    float f[8];
    f[0] = bf2f((unsigned short)(u.x & 0xffff)); f[1] = bf2f((unsigned short)(u.x >> 16));
    f[2] = bf2f((unsigned short)(u.y & 0xffff)); f[3] = bf2f((unsigned short)(u.y >> 16));
    f[4] = bf2f((unsigned short)(u.z & 0xffff)); f[5] = bf2f((unsigned short)(u.z >> 16));
    f[6] = bf2f((unsigned short)(u.w & 0xffff)); f[7] = bf2f((unsigned short)(u.w >> 16));

    float m = f[0];
#pragma unroll
    for (int j = 1; j < 8; ++j) m = fmaxf(m, f[j]);
    for (int o = 32; o > 0; o >>= 1) m = fmaxf(m, __shfl_down(m, o));
    if (lane == 0) red[w] = m;
    __syncthreads();
    float M = fmaxf(fmaxf(red[0], red[1]), fmaxf(red[2], red[3]));

    float e[8], s = 0.f;
#pragma unroll
    for (int j = 0; j < 8; ++j) { e[j] = __expf(f[j] - M); s += e[j]; }
    for (int o = 32; o > 0; o >>= 1) s += __shfl_down(s, o);
    if (lane == 0) red[4 + w] = s;
    __syncthreads();
    float invL = 1.0f / (red[4] + red[5] + red[6] + red[7]);

    uint4 ov;
    ov.x = pk2(e[0] * invL, e[1] * invL);
    ov.y = pk2(e[2] * invL, e[3] * invL);
    ov.z = pk2(e[4] * invL, e[5] * invL);
    ov.w = pk2(e[6] * invL, e[7] * invL);
    *reinterpret_cast<uint4*>(&T[(long)row * 2048 + tid * 8]) = ov;
}

// Cast 4 weight matrices (131072 fp32 each) to bf16, concatenated into W.
__global__ __launch_bounds__(256) void cast_w(
    const float* __restrict__ a, const float* __restrict__ b,
    const float* __restrict__ c, const float* __restrict__ d,
    short* __restrict__ W)
{
    const float* S[4] = {a, b, c, d};
    int sel = blockIdx.y;
    int i = (blockIdx.x * 256 + threadIdx.x) * 4;
    float4 f = *reinterpret_cast<const float4*>(&S[sel][i]);
    uint2 o;
    o.x = pk2(f.x, f.y);
    o.y = pk2(f.z, f.w);
    *reinterpret_cast<uint2*>(&W[sel * 131072 + i]) = o;
}

extern "C" void kernel_launch(void* const* d_in, const int* in_sizes, int n_in,
                              void* d_out, int out_size, void* d_ws, size_t ws_size,
                              hipStream_t stream)
{
    const float* q    = (const float*)d_in[0];
    const float* kk   = (const float*)d_in[1];
    const float* v    = (const float*)d_in[2];
    const float* Wphi = (const float*)d_in[3];
    const float* Wth  = (const float*)d_in[4];
    const float* Wg   = (const float*)d_in[5];
    const float* Wm   = (const float*)d_in[6];
    float* out = (float*)d_out;
    dim3 blk(256);

    // Per-batch workspace (shorts): Phi 1M | Th 1M | Gr 1M | T 4M | YtvT 1M = 8M shorts
    const long PB = 8388608;
    long ws_shorts = (long)(ws_size / 2);
    int NB = (int)((ws_shorts - 524288) / PB);
    if (NB > 8) NB = 8;
    if (NB < 1) NB = 1;

    short* Wb   = (short*)d_ws;              // 512K shorts
    short* Phi  = Wb + 524288;               // [NB][4096][256] = phi^T
    short* Th   = Phi + (long)NB * 1048576;  // [NB][4096][256]
    short* Gr   = Th + (long)NB * 1048576;   // [NB][256][4096] (flat == G[512][2048])
    short* T    = Gr + (long)NB * 1048576;   // [NB][2048][2048] = S^T, then attn^T
    short* YtvT = T + (long)NB * 4194304;    // [NB][4096][256]
    const short* WbPhi = Wb;
    const short* WbG   = Wb + 262144;
    const short* WbM   = Wb + 393216;

    const int LIN_M = 0x3FFFFFFF, LIN_S = 30;  // linear k addressing

    cast_w<<<dim3(128, 4), blk, 0, stream>>>(Wphi, Wth, Wg, Wm, Wb);

    for (int b0 = 0; b0 < 8; b0 += NB) {
        int nb = 8 - b0 < NB ? 8 - b0 : NB;
        const float* qb = q + (long)b0 * QS;
        const float* kb = kk + (long)b0 * QS;
        const float* vb = v + (long)b0 * QS;

        // conv-T merged (phi & theta): C[m=p][n=o], 1-KB-row fp32 staging
        // Phi[p][o] = sum_c q[c][p] * Wphi[o][c]   (M=4096, N=256, K=512)
        convmm<true, true><<<dim3(4, 16, nb * 2), blk, 0, stream>>>(
            qb, kb, WbPhi, 131072, Phi, (long)NB * 1048576,
            256, QS, 1048576);

        // conv-N: Gr[o][p] = sum_c Wg[o][c] * v[c][p]   (M=256, N=4096, K=512)
        convmm<false, false><<<dim3(16, 4, nb), blk, 0, stream>>>(
            vb, nullptr, WbG, 0, Gr, 0,
            4096, QS, 1048576);

        // score: T[m][n] = S^T = sum_{h,o} Phi[h*2048+m][o]*Th[h*2048+n][o]
        // k-panel: kmask=255, kshift=8, kpanel=2048*256  (M=N=2048, K=512)
        mm<128, 128, EPI_BF><<<dim3(16, 16, nb), blk, 0, stream>>>(
            Phi, Th, T, nullptr, nullptr,
            512, 256, 256, 2048, 255, 8, 524288,
            1048576, 1048576, 4194304, 0);

        softmax_row<<<dim3(2048 * nb), blk, 0, stream>>>(T);

        // AV: Yt[c'][m] = sum_n Gflat[c'][n] * T[m][n]  (M=512, N=2048, K=2048)
        mm<64, 128, EPI_YT><<<dim3(16, 8, nb), blk, 0, stream>>>(
            Gr, T, YtvT, nullptr, nullptr,
            2048, 2048, 2048, 256, LIN_M, LIN_S, 0,
            1048576, 4194304, 1048576, 0);

        // mask + residual: out[o][p] = sum_i WbM[o][i]*YtvT[p][i] + q + v
        mm<128, 128, EPI_OUT><<<dim3(32, 4, nb), blk, 0, stream>>>(
            WbM, YtvT, out + (long)b0 * QS, qb, vb,
            256, 256, 256, 4096, LIN_M, LIN_S, 0,
            0, 1048576, QS, QS);
    }
}

// Round 6
// 419.643 us; speedup vs baseline: 1.0735x; 1.0735x over previous
//
#include <hip/hip_runtime.h>
#include <hip/hip_bf16.h>
#include <math.h>

typedef __hip_bfloat16 hbf16;
typedef __attribute__((ext_vector_type(8))) short short8;   // 8 bf16 (4 VGPRs)
typedef __attribute__((ext_vector_type(4))) float f32x4;

static const long QS = 2097152;  // 512*4096 per-batch q/k/v/out elems

__device__ __forceinline__ unsigned short f2bf(float f) {
    hbf16 h = __float2bfloat16(f);
    return *reinterpret_cast<unsigned short*>(&h);
}
__device__ __forceinline__ float bf2f(unsigned short u) {
    unsigned x = ((unsigned)u) << 16;
    return __uint_as_float(x);
}
__device__ __forceinline__ unsigned pk2(float a, float b) {
    return (unsigned)f2bf(a) | ((unsigned)f2bf(b) << 16);
}

// async 16-B global->LDS (wave-uniform LDS base; HW adds lane*16.
// GLOBAL source address is PER-LANE and must include the lane offset!)
__device__ __forceinline__ void gload16(const void* g, void* l) {
    __builtin_amdgcn_global_load_lds(
        (const __attribute__((address_space(1))) void*)g,
        (__attribute__((address_space(3))) void*)l, 16, 0, 0);
}

// ---------------------------------------------------------------------------
// convmm: all three 1x1 convs in one kernel.
// Block = [256 p] x [all 256 o], K=512, BK=32, 512 threads (8 waves 2p x 4o).
// X (fp32 [512 c][4096 p]) read EXACTLY ONCE, in 1-KB contiguous k-rows via
// global_load_lds into Lf[32][256]; transposed+cast into Ps with m97 XOR-8
// super-row geometry (128-B rows, slot ((r&1)*4+c)^((r>>1)&7)): frag reads
// bank-conflict-free. Weights are NOT LDS-staged (L2-resident, per-lane
// short8 fragment loads, one-step prefetch).
// sel = z%3: 0 -> Phi[p][o], 1 -> Th[p][o], 2 -> Gr[o][p] (packed scatter).
// ---------------------------------------------------------------------------
__global__ __launch_bounds__(512, 2) void convmm(
    const float* __restrict__ Xq, const float* __restrict__ Xk,
    const float* __restrict__ Xv,
    const short* __restrict__ Wb,
    short* __restrict__ Phi, long selStride,   // Th = Phi + selStride
    short* __restrict__ Gr)
{
    __shared__ __align__(16) float Lf[32 * 256];   // 32 KB fp32 [k 32][p 256]
    __shared__ __align__(16) short Ps[128 * 64];   // 16 KB bf16, m97 super-rows

    const int tid = threadIdx.x;
    const int w = tid >> 6, lane = tid & 63;
    const int quad = lane >> 4, l16 = lane & 15;
    const int p0 = blockIdx.x * 256;
    const int sel = blockIdx.z % 3;
    const int bz = blockIdx.z / 3;

    const float* X = (sel == 0 ? Xq : sel == 1 ? Xk : Xv) + (long)bz * QS;
    const short* Wp = Wb + sel * 131072;

    const int wp = (w & 1) * 128;   // wave p-base
    const int wo = (w >> 1) * 64;   // wave o-base
    const int tp = tid & 255;       // transpose: p column owned
    const int kh = tid >> 8;        // transpose: k-half (16 k each)

    f32x4 acc[8][4];
#pragma unroll
    for (int i = 0; i < 8; ++i)
#pragma unroll
        for (int j = 0; j < 4; ++j) acc[i][j] = (f32x4){0.f, 0.f, 0.f, 0.f};

    // stage 32 k-rows x 256 p fp32; each wave-issue = one full 1-KB row.
    // LDS dest wave-uniform (HW adds lane*16); global src carries lane*4 floats.
    auto issueX = [&](int k0) {
#pragma unroll
        for (int i = 0; i < 4; ++i) {
            int r = i * 8 + w;
            gload16(X + (long)(k0 + r) * 4096 + p0 + lane * 4, Lf + r * 256);
        }
    };
    short8 bfn[4];
    auto loadW = [&](int k0) {
#pragma unroll
        for (int nt = 0; nt < 4; ++nt)
            bfn[nt] = *reinterpret_cast<const short8*>(
                &Wp[(long)(wo + nt * 16 + l16) * 512 + k0 + quad * 8]);
    };

    issueX(0);
    loadW(0);

    for (int k0 = 0; k0 < 512; k0 += 32) {
        __syncthreads();   // Lf(k0) landed (barrier drains vmcnt)

        // transpose + cast: Lf[k][p] -> Ps super-row layout
        float f[16];
#pragma unroll
        for (int j = 0; j < 16; ++j) f[j] = Lf[(kh * 16 + j) * 256 + tp];
        {
            int R = tp >> 1, h = tp & 1;
#pragma unroll
            for (int u = 0; u < 2; ++u) {
                uint4 pk;
                pk.x = pk2(f[u * 8 + 0], f[u * 8 + 1]);
                pk.y = pk2(f[u * 8 + 2], f[u * 8 + 3]);
                pk.z = pk2(f[u * 8 + 4], f[u * 8 + 5]);
                pk.w = pk2(f[u * 8 + 6], f[u * 8 + 7]);
                int c = kh * 2 + u;
                int s = (h * 4 + c) ^ (R & 7);
                *reinterpret_cast<uint4*>(&Ps[R * 64 + s * 8]) = pk;
            }
        }

        short8 bcur[4];
#pragma unroll
        for (int nt = 0; nt < 4; ++nt) bcur[nt] = bfn[nt];

        __syncthreads();   // Ps ready; Lf free for prefetch

        if (k0 + 32 < 512) { issueX(k0 + 32); loadW(k0 + 32); }

        short8 af[8];
#pragma unroll
        for (int mt = 0; mt < 8; ++mt) {
            int r = wp + mt * 16 + l16;
            int R = r >> 1;
            int s = ((r & 1) * 4 + quad) ^ (R & 7);
            af[mt] = *reinterpret_cast<const short8*>(&Ps[R * 64 + s * 8]);
        }
#pragma unroll
        for (int mt = 0; mt < 8; ++mt)
#pragma unroll
            for (int nt = 0; nt < 4; ++nt)
                acc[mt][nt] = __builtin_amdgcn_mfma_f32_16x16x32_bf16(
                    af[mt], bcur[nt], acc[mt][nt], 0, 0, 0);
    }

    // Epilogue. C/D layout: col(n=o) = lane&15, row(m=p) = quad*4 + reg.
    if (sel < 2) {
        short* Cp = Phi + (long)sel * selStride + (long)bz * 1048576;
#pragma unroll
        for (int mt = 0; mt < 8; ++mt)
#pragma unroll
            for (int nt = 0; nt < 4; ++nt)
#pragma unroll
                for (int reg = 0; reg < 4; ++reg) {
                    int gr = p0 + wp + mt * 16 + quad * 4 + reg;
                    int gc = wo + nt * 16 + l16;
                    Cp[(long)gr * 256 + gc] = (short)f2bf(acc[mt][nt][reg]);
                }
    } else {
        short* Cp = Gr + (long)bz * 1048576;
#pragma unroll
        for (int mt = 0; mt < 8; ++mt)
#pragma unroll
            for (int nt = 0; nt < 4; ++nt) {
                int gr = p0 + wp + mt * 16 + quad * 4;   // 4 consecutive p
                int gc = wo + nt * 16 + l16;             // o
                uint2 pk;
                pk.x = pk2(acc[mt][nt][0], acc[mt][nt][1]);
                pk.y = pk2(acc[mt][nt][2], acc[mt][nt][3]);
                *reinterpret_cast<uint2*>(&Cp[(long)gc * 4096 + gr]) = pk;
            }
    }
}

// ---------------------------------------------------------------------------
// BK=64 direct staging for the bf16 GEMMs (proven path).
// LDS row r = 64 shorts (128 B) = 8 chunk slots; slot s holds chunk s^(r&7).
// ---------------------------------------------------------------------------
template <int R>
__device__ __forceinline__ void stage_direct(const short* P, int ld, int row0,
                                             long koff, short* Ls) {
    const int tid = threadIdx.x;
    const int w = tid >> 6, lane = tid & 63;
    const int lrow = lane >> 3;
    const int s = lane & 7;
#pragma unroll
    for (int j = 0; j < R / 32; ++j) {
        int rowbase = w * (R / 4) + j * 8;
        int r = rowbase + lrow;
        int g = s ^ (r & 7);
        const short* ga = P + (long)(row0 + r) * ld + koff + g * 8;
        gload16(ga, Ls + rowbase * 64);
    }
}

#define EPI_BF 0   // bf16 C[row][col], ldc
#define EPI_YT 1   // AV: scatter to YtvT[4096][256]
#define EPI_OUT 2  // fp32 out + q + v residual, ldc=4096

// Generic NT MFMA GEMM (direct bf16 operands): C[m][n] = sum_k A[m][k]B[n][k]
// XM = grid mapping: 0 normal (x=n, y=m, z=batch)
//                    1 score  (x=batch, y=tile: m=y>>4, n=y&15)   [batch->XCD]
//                    2 AV     (x=btile: n=x&15, batch=x>>4; y=m)  [T-tile->XCD]
template <int TM, int TN, int EPI, int XM>
__global__ __launch_bounds__(256) void mm(
    const short* __restrict__ A, const short* __restrict__ B,
    void* __restrict__ C, const float* __restrict__ Rq, const float* __restrict__ Rv,
    int K, int lda, int ldb, int ldc, int kmask, int kshift, long kpanel,
    long bsA, long bsB, long bsC, long bsR)
{
    __shared__ __align__(16) short As[TM * 64];
    __shared__ __align__(16) short Bs[TN * 64];

    const int tid = threadIdx.x;
    const int w = tid >> 6, lane = tid & 63;
    const int quad = lane >> 4, l16 = lane & 15;

    int m0, n0, bz;
    if constexpr (XM == 0) {
        m0 = blockIdx.y * TM; n0 = blockIdx.x * TN; bz = blockIdx.z;
    } else if constexpr (XM == 1) {
        bz = blockIdx.x; m0 = (blockIdx.y >> 4) * TM; n0 = (blockIdx.y & 15) * TN;
    } else {
        bz = blockIdx.x >> 4; n0 = (blockIdx.x & 15) * TN; m0 = blockIdx.y * TM;
    }

    A += (long)bz * bsA;
    B += (long)bz * bsB;
    const long cb = (long)bz * bsC;
    if constexpr (EPI == EPI_OUT) { Rq += (long)bz * bsR; Rv += (long)bz * bsR; }

    constexpr int WM = TM / 2;
    constexpr int MT = WM / 16;
    const int wm = (w & 1) * WM;
    const int wn = (w >> 1) * 64;

    f32x4 acc[MT][4];
#pragma unroll
    for (int i = 0; i < MT; ++i)
#pragma unroll
        for (int j = 0; j < 4; ++j) acc[i][j] = (f32x4){0.f, 0.f, 0.f, 0.f};

    for (int k0 = 0; k0 < K; k0 += 64) {
        __syncthreads();
        long koff = (long)(k0 & kmask) + (long)(k0 >> kshift) * kpanel;
        stage_direct<TM>(A, lda, m0, koff, As);
        stage_direct<TN>(B, ldb, n0, koff, Bs);
        __syncthreads();

#pragma unroll
        for (int ks = 0; ks < 2; ++ks) {
            short8 af[MT], bfr[4];
#pragma unroll
            for (int mt = 0; mt < MT; ++mt) {
                int r = wm + mt * 16 + l16;
                int s = (ks * 4 + quad) ^ (r & 7);
                af[mt] = *reinterpret_cast<const short8*>(&As[r * 64 + s * 8]);
            }
#pragma unroll
            for (int nt = 0; nt < 4; ++nt) {
                int r = wn + nt * 16 + l16;
                int s = (ks * 4 + quad) ^ (r & 7);
                bfr[nt] = *reinterpret_cast<const short8*>(&Bs[r * 64 + s * 8]);
            }
#pragma unroll
            for (int mt = 0; mt < MT; ++mt)
#pragma unroll
                for (int nt = 0; nt < 4; ++nt)
                    acc[mt][nt] = __builtin_amdgcn_mfma_f32_16x16x32_bf16(
                        af[mt], bfr[nt], acc[mt][nt], 0, 0, 0);
        }
    }

#pragma unroll
    for (int mt = 0; mt < MT; ++mt)
#pragma unroll
        for (int nt = 0; nt < 4; ++nt)
#pragma unroll
            for (int reg = 0; reg < 4; ++reg) {
                int gr = m0 + wm + mt * 16 + quad * 4 + reg;
                int gc = n0 + wn + nt * 16 + l16;
                float vacc = acc[mt][nt][reg];
                if constexpr (EPI == EPI_BF) {
                    ((short*)C)[cb + (long)gr * ldc + gc] = (short)f2bf(vacc);
                } else if constexpr (EPI == EPI_YT) {
                    long a = (long)gc * 256 + (long)(gr & 1) * 524288 + (gr >> 1);
                    ((short*)C)[cb + a] = (short)f2bf(vacc);
                } else {
                    long a = (long)gr * 4096 + gc;
                    ((float*)C)[cb + a] = vacc + Rq[a] + Rv[a];
                }
            }
}

// Row softmax of T[nrows][2048] bf16 in place (one block per row).
__global__ __launch_bounds__(256) void softmax_row(short* __restrict__ T) {
    const int row = blockIdx.x;
    const int tid = threadIdx.x;
    const int w = tid >> 6, lane = tid & 63;
    __shared__ float red[8];

    uint4 u = *reinterpret_cast<const uint4*>(&T[(long)row * 2048 + tid * 8]);
    float f[8];
    f[0] = bf2f((unsigned short)(u.x & 0xffff)); f[1] = bf2f((unsigned short)(u.x >> 16));
    f[2] = bf2f((unsigned short)(u.y & 0xffff)); f[3] = bf2f((unsigned short)(u.y >> 16));
    f[4] = bf2f((unsigned short)(u.z & 0xffff)); f[5] = bf2f((unsigned short)(u.z >> 16));
    f[6] = bf2f((unsigned short)(u.w & 0xffff)); f[7] = bf2f((unsigned short)(u.w >> 16));

    float m = f[0];
#pragma unroll
    for (int j = 1; j < 8; ++j) m = fmaxf(m, f[j]);
    for (int o = 32; o > 0; o >>= 1) m = fmaxf(m, __shfl_down(m, o));
    if (lane == 0) red[w] = m;
    __syncthreads();
    float M = fmaxf(fmaxf(red[0], red[1]), fmaxf(red[2], red[3]));

    float e[8], s = 0.f;
#pragma unroll
    for (int j = 0; j < 8; ++j) { e[j] = __expf(f[j] - M); s += e[j]; }
    for (int o = 32; o > 0; o >>= 1) s += __shfl_down(s, o);
    if (lane == 0) red[4 + w] = s;
    __syncthreads();
    float invL = 1.0f / (red[4] + red[5] + red[6] + red[7]);

    uint4 ov;
    ov.x = pk2(e[0] * invL, e[1] * invL);
    ov.y = pk2(e[2] * invL, e[3] * invL);
    ov.z = pk2(e[4] * invL, e[5] * invL);
    ov.w = pk2(e[6] * invL, e[7] * invL);
    *reinterpret_cast<uint4*>(&T[(long)row * 2048 + tid * 8]) = ov;
}

// Cast 4 weight matrices (131072 fp32 each) to bf16, concatenated into W.
__global__ __launch_bounds__(256) void cast_w(
    const float* __restrict__ a, const float* __restrict__ b,
    const float* __restrict__ c, const float* __restrict__ d,
    short* __restrict__ W)
{
    const float* S[4] = {a, b, c, d};
    int sel = blockIdx.y;
    int i = (blockIdx.x * 256 + threadIdx.x) * 4;
    float4 f = *reinterpret_cast<const float4*>(&S[sel][i]);
    uint2 o;
    o.x = pk2(f.x, f.y);
    o.y = pk2(f.z, f.w);
    *reinterpret_cast<uint2*>(&W[sel * 131072 + i]) = o;
}

extern "C" void kernel_launch(void* const* d_in, const int* in_sizes, int n_in,
                              void* d_out, int out_size, void* d_ws, size_t ws_size,
                              hipStream_t stream)
{
    const float* q    = (const float*)d_in[0];
    const float* kk   = (const float*)d_in[1];
    const float* v    = (const float*)d_in[2];
    const float* Wphi = (const float*)d_in[3];
    const float* Wth  = (const float*)d_in[4];
    const float* Wg   = (const float*)d_in[5];
    const float* Wm   = (const float*)d_in[6];
    float* out = (float*)d_out;
    dim3 blk(256);

    // Per-batch workspace (shorts): Phi 1M | Th 1M | Gr 1M | T 4M | YtvT 1M = 8M shorts
    const long PB = 8388608;
    long ws_shorts = (long)(ws_size / 2);
    int NB = (int)((ws_shorts - 524288) / PB);
    if (NB > 8) NB = 8;
    if (NB < 1) NB = 1;

    short* Wb   = (short*)d_ws;              // 512K shorts
    short* Phi  = Wb + 524288;               // [NB][4096][256] = phi^T
    short* Th   = Phi + (long)NB * 1048576;  // [NB][4096][256]
    short* Gr   = Th + (long)NB * 1048576;   // [NB][256][4096] (flat == G[512][2048])
    short* T    = Gr + (long)NB * 1048576;   // [NB][2048][2048] = S^T, then attn^T
    short* YtvT = T + (long)NB * 4194304;    // [NB][4096][256]
    const short* WbM = Wb + 393216;

    const int LIN_M = 0x3FFFFFFF, LIN_S = 30;  // linear k addressing

    cast_w<<<dim3(128, 4), blk, 0, stream>>>(Wphi, Wth, Wg, Wm, Wb);

    for (int b0 = 0; b0 < 8; b0 += NB) {
        int nb = 8 - b0 < NB ? 8 - b0 : NB;
        const float* qb = q + (long)b0 * QS;
        const float* kb = kk + (long)b0 * QS;
        const float* vb = v + (long)b0 * QS;

        // all three convs: X read once, 1-KB rows, z = 3*nb
        convmm<<<dim3(16, 1, nb * 3), dim3(512), 0, stream>>>(
            qb, kb, vb, Wb, Phi, (long)NB * 1048576, Gr);

        // score: T[m][n] = S^T = sum_{h,o} Phi[h*2048+m][o]*Th[h*2048+n][o]
        // batch -> XCD affinity: x = batch, y = 256 tiles
        mm<128, 128, EPI_BF, 1><<<dim3(nb, 256), blk, 0, stream>>>(
            Phi, Th, T, nullptr, nullptr,
            512, 256, 256, 2048, 255, 8, 524288,
            1048576, 1048576, 4194304, 0);

        softmax_row<<<dim3(2048 * nb), blk, 0, stream>>>(T);

        // AV: Yt[c'][m] = sum_n Gflat[c'][n] * T[m][n]  (M=512, N=2048, K=2048)
        // T-tile -> XCD affinity: x = (batch,n)-tile, y = m
        mm<64, 128, EPI_YT, 2><<<dim3(16 * nb, 8), blk, 0, stream>>>(
            Gr, T, YtvT, nullptr, nullptr,
            2048, 2048, 2048, 256, LIN_M, LIN_S, 0,
            1048576, 4194304, 1048576, 0);

        // mask + residual: out[o][p] = sum_i WbM[o][i]*YtvT[p][i] + q + v
        mm<128, 128, EPI_OUT, 0><<<dim3(32, 4, nb), blk, 0, stream>>>(
            WbM, YtvT, out + (long)b0 * QS, qb, vb,
            256, 256, 256, 4096, LIN_M, LIN_S, 0,
            0, 1048576, QS, QS);
    }
}